// Round 1
// baseline (4077.160 us; speedup 1.0000x reference)
//
#include <hip/hip_runtime.h>
#include <climits>
#include <math.h>

// Problem constants (from reference setup_inputs)
#define Bc   2
#define Tc   2048
#define Dc   2048
#define Nc   16
#define KHc  8
#define Hc   128
#define Sc   2048
#define GRPc (Nc / KHc)   // 2 q-heads per kv-head

constexpr float EPSc    = 1e-6f;
constexpr float KMASKc  = -0.7f * 3.4028234663852886e38f;  // -0.7 * FLT_MAX
constexpr float SCALEc  = 0.08838834764831843f;            // 1/sqrt(128)

// ---------------------------------------------------------------------------
// meta: per batch -> meta[b] = argmax index of seg (first occurrence),
//                    meta[Bc+b] = start (start_ind<0 ? num_left_pad : start_ind)
// ---------------------------------------------------------------------------
__global__ void meta_kernel(const int* __restrict__ seg,
                            const int* __restrict__ start_ind,
                            int* __restrict__ meta)
{
    int b = blockIdx.x;
    __shared__ int s_max, s_amax, s_nz;
    if (threadIdx.x == 0) { s_max = INT_MIN; s_amax = Tc; s_nz = Tc; }
    __syncthreads();
    int lmax = INT_MIN;
    for (int t = threadIdx.x; t < Tc; t += blockDim.x)
        lmax = max(lmax, seg[b * Tc + t]);
    atomicMax(&s_max, lmax);
    __syncthreads();
    int mv = s_max;
    int lamax = Tc, lnz = Tc;
    for (int t = threadIdx.x; t < Tc; t += blockDim.x) {
        int v = seg[b * Tc + t];
        if (v == mv) lamax = min(lamax, t);
        if (v != 0)  lnz   = min(lnz, t);
    }
    atomicMin(&s_amax, lamax);
    atomicMin(&s_nz, lnz);
    __syncthreads();
    if (threadIdx.x == 0) {
        meta[b] = s_amax;                        // argmax (first max index)
        int st = start_ind[b];
        meta[Bc + b] = (st < 0) ? s_nz : st;     // start
    }
}

// ---------------------------------------------------------------------------
// fp32 tiled GEMM: C[M,N] = A[M,K] @ B[K,N], all row-major.
// 64x64 tile, BK=16, 256 threads, 4x4 per thread. Requires M%64==N%64==K%16==0.
// ---------------------------------------------------------------------------
__global__ __launch_bounds__(256) void gemm64(const float* __restrict__ A,
                                              const float* __restrict__ B,
                                              float* __restrict__ C,
                                              int M, int N, int K)
{
    __shared__ float As[16][68];   // [k][m], pad 68 to break write conflicts
    __shared__ float Bs[16][68];   // [k][n]
    int tid = threadIdx.x;
    int tx = tid & 15, ty = tid >> 4;
    int bm = blockIdx.y * 64, bn = blockIdx.x * 64;
    float acc[4][4] = {};
    for (int k0 = 0; k0 < K; k0 += 16) {
        {
            // A tile 64x16 (one float4 per thread)
            int r = tid >> 2, c = (tid & 3) * 4;
            float4 a4 = *(const float4*)&A[(size_t)(bm + r) * K + k0 + c];
            As[c + 0][r] = a4.x; As[c + 1][r] = a4.y;
            As[c + 2][r] = a4.z; As[c + 3][r] = a4.w;
            // B tile 16x64 (one float4 per thread)
            int rb = tid >> 4, cb = (tid & 15) * 4;
            *(float4*)&Bs[rb][cb] = *(const float4*)&B[(size_t)(k0 + rb) * N + bn + cb];
        }
        __syncthreads();
#pragma unroll
        for (int k = 0; k < 16; ++k) {
            float4 a4 = *(const float4*)&As[k][ty * 4];
            float4 b4 = *(const float4*)&Bs[k][tx * 4];
            float av[4] = {a4.x, a4.y, a4.z, a4.w};
            float bv[4] = {b4.x, b4.y, b4.z, b4.w};
#pragma unroll
            for (int i = 0; i < 4; ++i)
#pragma unroll
                for (int j = 0; j < 4; ++j)
                    acc[i][j] = fmaf(av[i], bv[j], acc[i][j]);
        }
        __syncthreads();
    }
#pragma unroll
    for (int i = 0; i < 4; ++i) {
        size_t row = (size_t)(bm + ty * 4 + i);
        float4 v; v.x = acc[i][0]; v.y = acc[i][1]; v.z = acc[i][2]; v.w = acc[i][3];
        *(float4*)&C[row * N + bn + tx * 4] = v;
    }
}

// ---------------------------------------------------------------------------
// Fused per-head RMSNorm + RoPE, in place on Q (N heads) and Kf (KH heads).
// One wave per (b, t, head) row of 128.
// ---------------------------------------------------------------------------
__global__ __launch_bounds__(256) void norm_rope(float* __restrict__ Q,
                                                 float* __restrict__ Kf,
                                                 const float* __restrict__ qw,
                                                 const float* __restrict__ kw,
                                                 const int* __restrict__ seg,
                                                 const int* __restrict__ meta,
                                                 const int* __restrict__ cur_ptr)
{
    int row  = blockIdx.x * 4 + (threadIdx.x >> 6);
    int lane = threadIdx.x & 63;
    const int HH = Nc + KHc;   // 24
    int hh = row % HH;
    int bt = row / HH;
    int t = bt % Tc;
    int b = bt / Tc;

    float* ptr; const float* w;
    if (hh < Nc) { ptr = Q  + ((size_t)(b * Tc + t) * Nc  + hh)        * Hc; w = qw; }
    else         { ptr = Kf + ((size_t)(b * Tc + t) * KHc + (hh - Nc)) * Hc; w = kw; }

    float v1 = ptr[lane], v2 = ptr[lane + 64];
    float ssq = v1 * v1 + v2 * v2;
#pragma unroll
    for (int off = 1; off < 64; off <<= 1) ssq += __shfl_xor(ssq, off);
    float rinv = rsqrtf(ssq * (1.0f / Hc) + EPSc);

    int cur = cur_ptr[0];
    int sgv = seg[b * Tc + t];
    long long pos = (sgv != 0) ? (long long)(t - meta[b]) : (long long)(1 << 30);
    float posf = (float)(pos + (long long)cur);

    // inv_freq = theta^(-lane/64) = 2^(-lane/64 * log2(1e6))
    float inv_freq = exp2f(-(float)lane * (19.931568569324174f / 64.0f));
    float ang = posf * inv_freq;
    float s, c;
    sincosf(ang, &s, &c);

    float n1 = w[lane] * v1 * rinv;
    float n2 = w[lane + 64] * v2 * rinv;
    ptr[lane]      = n1 * c - n2 * s;
    ptr[lane + 64] = n2 * c + n1 * s;
}

// ---------------------------------------------------------------------------
// Flash attention (fp32): block = 256 threads per (b, head, 32-row q-tile).
// K/V chunk source: fresh (normed+roped) for s in [cur, cur+T), else cache.
// Exact reference mask: causal (s <= cur+t) AND kv_seg(s)==segment_ids[b,t],
// masked logits = KMASK (so fully-masked rows -> uniform softmax, as ref).
// ---------------------------------------------------------------------------
__global__ __launch_bounds__(256) void flash_attn(const float* __restrict__ Q,
                                                  const float* __restrict__ Kf,
                                                  const float* __restrict__ Vf,
                                                  const float* __restrict__ kc,
                                                  const float* __restrict__ vc,
                                                  const int* __restrict__ seg,
                                                  const int* __restrict__ meta,
                                                  const int* __restrict__ cur_ptr,
                                                  float* __restrict__ O)
{
    __shared__ float Qs[32][132];
    __shared__ float Ks[32][132];
    __shared__ float Vs[32][132];
    __shared__ float Ps[32][33];

    int tid = threadIdx.x;
    int bid = blockIdx.x;
    int qt = bid & (Tc / 32 - 1);       // 64 q-tiles
    int n  = (bid >> 6) & (Nc - 1);
    int b  = bid >> 10;
    int kh = n / GRPc;
    int cur = cur_ptr[0];
    int startb = meta[Bc + b];

    int r  = tid >> 3;      // 0..31 row in tile
    int c8 = tid & 7;       // 8 threads per row
    int h0 = c8 * 16;       // 16-wide slice of H per thread
    int t_row = qt * 32 + r;
    int sgq = seg[b * Tc + t_row];

    // load Q tile (32 x 128)
#pragma unroll
    for (int i = 0; i < 4; ++i) {
        int flat = (tid + 256 * i) * 4;
        int rr = flat >> 7, cc = flat & 127;
        *(float4*)&Qs[rr][cc] =
            *(const float4*)&Q[((size_t)(b * Tc + qt * 32 + rr) * Nc + n) * Hc + cc];
    }

    float o[16];
#pragma unroll
    for (int i = 0; i < 16; ++i) o[i] = 0.f;
    float m_i = -INFINITY, l_i = 0.f;

    for (int s0 = 0; s0 < Sc; s0 += 32) {
        // stage K/V chunk (32 x 128), fresh-vs-cache per row
#pragma unroll
        for (int i = 0; i < 4; ++i) {
            int flat = (tid + 256 * i) * 4;
            int rr = flat >> 7, cc = flat & 127;
            int s = s0 + rr;
            const float *kp, *vp;
            if (s >= cur && s < cur + Tc) {
                size_t off = ((size_t)(b * Tc + (s - cur)) * KHc + kh) * Hc + cc;
                kp = Kf + off; vp = Vf + off;
            } else {
                size_t off = ((size_t)(b * Sc + s) * KHc + kh) * Hc + cc;
                kp = kc + off; vp = vc + off;
            }
            *(float4*)&Ks[rr][cc] = *(const float4*)kp;
            *(float4*)&Vs[rr][cc] = *(const float4*)vp;
        }
        __syncthreads();

        // scores: thread computes cols j = c8*4 + jj  (4 dots of 128)
        float sc4[4] = {0.f, 0.f, 0.f, 0.f};
#pragma unroll 8
        for (int kk = 0; kk < 32; ++kk) {
            float4 q4 = *(const float4*)&Qs[r][kk * 4];
#pragma unroll
            for (int jj = 0; jj < 4; ++jj) {
                float4 k4 = *(const float4*)&Ks[c8 * 4 + jj][kk * 4];
                sc4[jj] = fmaf(q4.x, k4.x, sc4[jj]);
                sc4[jj] = fmaf(q4.y, k4.y, sc4[jj]);
                sc4[jj] = fmaf(q4.z, k4.z, sc4[jj]);
                sc4[jj] = fmaf(q4.w, k4.w, sc4[jj]);
            }
        }
        // scale + mask (exact reference semantics)
        float mloc = -INFINITY;
#pragma unroll
        for (int jj = 0; jj < 4; ++jj) {
            int s = s0 + c8 * 4 + jj;
            bool causal = (s <= cur + t_row);
            int kvseg = (s >= startb && s < cur + Tc) ? 1 : 0;
            bool ok = causal && (kvseg == sgq);
            sc4[jj] = ok ? sc4[jj] * SCALEc : KMASKc;
            mloc = fmaxf(mloc, sc4[jj]);
        }
        mloc = fmaxf(mloc, __shfl_xor(mloc, 1));
        mloc = fmaxf(mloc, __shfl_xor(mloc, 2));
        mloc = fmaxf(mloc, __shfl_xor(mloc, 4));
        float m_new = fmaxf(m_i, mloc);
        float lsum = 0.f;
#pragma unroll
        for (int jj = 0; jj < 4; ++jj) {
            float p = expf(sc4[jj] - m_new);
            Ps[r][c8 * 4 + jj] = p;
            lsum += p;
        }
        lsum += __shfl_xor(lsum, 1);
        lsum += __shfl_xor(lsum, 2);
        lsum += __shfl_xor(lsum, 4);
        float alpha = expf(m_i - m_new);   // m_i=-inf first iter -> 0
        l_i = l_i * alpha + lsum;
        m_i = m_new;
#pragma unroll
        for (int i = 0; i < 16; ++i) o[i] *= alpha;
        __syncthreads();

        // PV: o[r][h0..h0+15] += sum_j Ps[r][j] * Vs[j][h]
#pragma unroll 4
        for (int j = 0; j < 32; ++j) {
            float pj = Ps[r][j];
#pragma unroll
            for (int ii = 0; ii < 4; ++ii) {
                float4 v4 = *(const float4*)&Vs[j][h0 + ii * 4];
                o[ii * 4 + 0] = fmaf(pj, v4.x, o[ii * 4 + 0]);
                o[ii * 4 + 1] = fmaf(pj, v4.y, o[ii * 4 + 1]);
                o[ii * 4 + 2] = fmaf(pj, v4.z, o[ii * 4 + 2]);
                o[ii * 4 + 3] = fmaf(pj, v4.w, o[ii * 4 + 3]);
            }
        }
        __syncthreads();
    }

    float linv = 1.0f / l_i;
    float* op = O + ((size_t)(b * Tc + t_row) * Nc + n) * Hc + h0;
#pragma unroll
    for (int ii = 0; ii < 4; ++ii) {
        float4 v;
        v.x = o[ii * 4 + 0] * linv; v.y = o[ii * 4 + 1] * linv;
        v.z = o[ii * 4 + 2] * linv; v.w = o[ii * 4 + 3] * linv;
        *(float4*)&op[ii * 4] = v;
    }
}

// ---------------------------------------------------------------------------
extern "C" void kernel_launch(void* const* d_in, const int* in_sizes, int n_in,
                              void* d_out, int out_size, void* d_ws, size_t ws_size,
                              hipStream_t stream)
{
    const float* x        = (const float*)d_in[0];
    const float* q_w      = (const float*)d_in[1];
    const float* k_w      = (const float*)d_in[2];
    const float* v_w      = (const float*)d_in[3];
    const float* o_w      = (const float*)d_in[4];
    const float* q_norm_w = (const float*)d_in[5];
    const float* k_norm_w = (const float*)d_in[6];
    const float* k_cache  = (const float*)d_in[7];
    const float* v_cache  = (const float*)d_in[8];
    const int*   seg      = (const int*)d_in[9];
    const int*   startind = (const int*)d_in[10];
    const int*   cur_ptr  = (const int*)d_in[11];
    float* out = (float*)d_out;
    (void)in_sizes; (void)n_in; (void)out_size; (void)ws_size;

    // workspace layout (fp32): [meta 64 ints][Q][Kf][Vf][O]  (~100.7 MB)
    float* ws   = (float*)d_ws;
    int*   meta = (int*)d_ws;
    float* Qbuf = ws + 64;
    float* Kf   = Qbuf + (size_t)Bc * Tc * Nc  * Hc;
    float* Vf   = Kf   + (size_t)Bc * Tc * KHc * Hc;
    float* Obuf = Vf   + (size_t)Bc * Tc * KHc * Hc;

    meta_kernel<<<Bc, 256, 0, stream>>>(seg, startind, meta);

    dim3 gq(Nc * Hc / 64, Bc * Tc / 64);
    gemm64<<<gq, 256, 0, stream>>>(x, q_w, Qbuf, Bc * Tc, Nc * Hc, Dc);
    dim3 gk(KHc * Hc / 64, Bc * Tc / 64);
    gemm64<<<gk, 256, 0, stream>>>(x, k_w, Kf, Bc * Tc, KHc * Hc, Dc);
    gemm64<<<gk, 256, 0, stream>>>(x, v_w, Vf, Bc * Tc, KHc * Hc, Dc);

    norm_rope<<<Bc * Tc * (Nc + KHc) / 4, 256, 0, stream>>>(
        Qbuf, Kf, q_norm_w, k_norm_w, seg, meta, cur_ptr);

    flash_attn<<<Bc * Nc * (Tc / 32), 256, 0, stream>>>(
        Qbuf, Kf, Vf, k_cache, v_cache, seg, meta, cur_ptr, Obuf);

    dim3 go(Dc / 64, Bc * Tc / 64);
    gemm64<<<go, 256, 0, stream>>>(Obuf, o_w, out, Bc * Tc, Dc, Nc * Hc);
}

// Round 2
// 627.035 us; speedup vs baseline: 6.5023x; 6.5023x over previous
//
#include <hip/hip_runtime.h>
#include <climits>
#include <math.h>

#define Bc   2
#define Tc   2048
#define Dc   2048
#define Nc   16
#define KHc  8
#define Hc   128
#define Sc   2048

constexpr float EPSc   = 1e-6f;
constexpr float KMASKc = -0.7f * 3.4028234663852886e38f;
constexpr float SCALEc = 0.08838834764831843f;   // 1/sqrt(128)

typedef short short8 __attribute__((ext_vector_type(8)));
typedef float float4v __attribute__((ext_vector_type(4)));

union U16x8 { uint4 u; short8 s8; unsigned short us[8]; };

__device__ __forceinline__ unsigned short f2bf(float f) {
    union { float f; unsigned u; } v; v.f = f;
    unsigned r = v.u + 0x7FFFu + ((v.u >> 16) & 1u);
    return (unsigned short)(r >> 16);
}
__device__ __forceinline__ float bf2f(unsigned short u) {
    union { unsigned u; float f; } v; v.u = ((unsigned)u) << 16;
    return v.f;
}

// ---------------------------------------------------------------------------
// meta[b] = argmax(seg) first index; meta[Bc+b] = start
// ---------------------------------------------------------------------------
__global__ void meta_kernel(const int* __restrict__ seg,
                            const int* __restrict__ start_ind,
                            int* __restrict__ meta)
{
    int b = blockIdx.x;
    __shared__ int s_max, s_amax, s_nz;
    if (threadIdx.x == 0) { s_max = INT_MIN; s_amax = Tc; s_nz = Tc; }
    __syncthreads();
    int lmax = INT_MIN;
    for (int t = threadIdx.x; t < Tc; t += blockDim.x)
        lmax = max(lmax, seg[b * Tc + t]);
    atomicMax(&s_max, lmax);
    __syncthreads();
    int mv = s_max;
    int lamax = Tc, lnz = Tc;
    for (int t = threadIdx.x; t < Tc; t += blockDim.x) {
        int v = seg[b * Tc + t];
        if (v == mv) lamax = min(lamax, t);
        if (v != 0)  lnz   = min(lnz, t);
    }
    atomicMin(&s_amax, lamax);
    atomicMin(&s_nz, lnz);
    __syncthreads();
    if (threadIdx.x == 0) {
        meta[b] = s_amax;
        int st = start_ind[b];
        meta[Bc + b] = (st < 0) ? s_nz : st;
    }
}

// ---------------------------------------------------------------------------
// cast fp32 -> bf16, 8 elems/thread
// ---------------------------------------------------------------------------
__global__ void cast_bf16(const float* __restrict__ in, unsigned short* __restrict__ out)
{
    size_t base = ((size_t)blockIdx.x * 256 + threadIdx.x) * 8;
    float4 a = *(const float4*)&in[base];
    float4 b = *(const float4*)&in[base + 4];
    U16x8 o;
    o.us[0] = f2bf(a.x); o.us[1] = f2bf(a.y); o.us[2] = f2bf(a.z); o.us[3] = f2bf(a.w);
    o.us[4] = f2bf(b.x); o.us[5] = f2bf(b.y); o.us[6] = f2bf(b.z); o.us[7] = f2bf(b.w);
    *(uint4*)&out[base] = o.u;
}

// cache fill: Kall/Vall = bf16(cache), same flat layout
__global__ void cache_cast(const float* __restrict__ kc, const float* __restrict__ vc,
                           unsigned short* __restrict__ Kall, unsigned short* __restrict__ Vall)
{
    size_t base = ((size_t)blockIdx.x * 256 + threadIdx.x) * 8;
    {
        float4 a = *(const float4*)&kc[base];
        float4 b = *(const float4*)&kc[base + 4];
        U16x8 o;
        o.us[0] = f2bf(a.x); o.us[1] = f2bf(a.y); o.us[2] = f2bf(a.z); o.us[3] = f2bf(a.w);
        o.us[4] = f2bf(b.x); o.us[5] = f2bf(b.y); o.us[6] = f2bf(b.z); o.us[7] = f2bf(b.w);
        *(uint4*)&Kall[base] = o.u;
    }
    {
        float4 a = *(const float4*)&vc[base];
        float4 b = *(const float4*)&vc[base + 4];
        U16x8 o;
        o.us[0] = f2bf(a.x); o.us[1] = f2bf(a.y); o.us[2] = f2bf(a.z); o.us[3] = f2bf(a.w);
        o.us[4] = f2bf(b.x); o.us[5] = f2bf(b.y); o.us[6] = f2bf(b.z); o.us[7] = f2bf(b.w);
        *(uint4*)&Vall[base] = o.u;
    }
}

// ---------------------------------------------------------------------------
// transpose + cast: in fp32 [R][C] -> out bf16 [C][R]
// ---------------------------------------------------------------------------
__global__ __launch_bounds__(256) void transpose_cast(const float* __restrict__ in,
                                                      unsigned short* __restrict__ out,
                                                      int R, int C)
{
    __shared__ float tile[32][33];
    int tid = threadIdx.x;
    int c0 = blockIdx.x * 32, r0 = blockIdx.y * 32;
#pragma unroll
    for (int i = 0; i < 4; ++i) {
        int row = (tid >> 5) + i * 8, col = tid & 31;
        tile[row][col] = in[(size_t)(r0 + row) * C + c0 + col];
    }
    __syncthreads();
#pragma unroll
    for (int i = 0; i < 4; ++i) {
        int rowo = (tid >> 5) + i * 8, colo = tid & 31;   // rowo: c-index, colo: r-index
        out[(size_t)(c0 + rowo) * R + r0 + colo] = f2bf(tile[colo][rowo]);
    }
}

// ---------------------------------------------------------------------------
// bf16 MFMA GEMM: C[M,N] = A[M,K] * B[K,N], B given TRANSPOSED (BT[N][K]).
// 128x128 tile, BK=32, 256 threads (4 waves 2x2), 16x16x32 mfma.
// out_fp32: 1 -> fp32 store, 0 -> bf16 store.
// ---------------------------------------------------------------------------
__global__ __launch_bounds__(256, 2) void gemm_mfma(const unsigned short* __restrict__ A,
                                                    const unsigned short* __restrict__ BT,
                                                    void* __restrict__ Cout,
                                                    int M, int N, int K, int out_fp32)
{
    __shared__ __align__(16) unsigned short As[128 * 40];   // rows padded 32->40
    __shared__ __align__(16) unsigned short Bs[128 * 40];
    int tid = threadIdx.x;
    int lane = tid & 63, w = tid >> 6;
    int quad = lane >> 4, l15 = lane & 15;
    int bm = blockIdx.y * 128, bn = blockIdx.x * 128;
    int wm = (w >> 1) * 64, wn = (w & 1) * 64;

    float4v acc[16];
#pragma unroll
    for (int i = 0; i < 16; ++i) acc[i] = (float4v)0.f;

    for (int k0 = 0; k0 < K; k0 += 32) {
        __syncthreads();
#pragma unroll
        for (int i = 0; i < 4; ++i) {
            int c = tid + 256 * i;
            int row = (c >> 2) & 127, part = c & 3;
            const unsigned short* src =
                (c < 512 ? A + (size_t)(bm + row) * K : BT + (size_t)(bn + row) * K)
                + k0 + part * 8;
            unsigned short* dst = (c < 512 ? As : Bs) + row * 40 + part * 8;
            *(uint4*)dst = *(const uint4*)src;
        }
        __syncthreads();
        short8 af[4];
#pragma unroll
        for (int mi = 0; mi < 4; ++mi)
            af[mi] = *(const short8*)&As[(wm + mi * 16 + l15) * 40 + quad * 8];
#pragma unroll
        for (int ni = 0; ni < 4; ++ni) {
            short8 bf = *(const short8*)&Bs[(wn + ni * 16 + l15) * 40 + quad * 8];
#pragma unroll
            for (int mi = 0; mi < 4; ++mi)
                acc[mi * 4 + ni] = __builtin_amdgcn_mfma_f32_16x16x32_bf16(af[mi], bf, acc[mi * 4 + ni], 0, 0, 0);
        }
    }

#pragma unroll
    for (int mi = 0; mi < 4; ++mi)
#pragma unroll
        for (int ni = 0; ni < 4; ++ni)
#pragma unroll
            for (int reg = 0; reg < 4; ++reg) {
                int row = bm + wm + mi * 16 + quad * 4 + reg;
                int col = bn + wn + ni * 16 + l15;
                float v = acc[mi * 4 + ni][reg];
                if (out_fp32) ((float*)Cout)[(size_t)row * N + col] = v;
                else ((unsigned short*)Cout)[(size_t)row * N + col] = f2bf(v);
            }
}

// ---------------------------------------------------------------------------
// RMSNorm + RoPE on bf16 rows. One wave per (b,t,head-slot):
// slot 0..15: Q (in-place on Qh), 16..23: K -> Kall[cur+t], 24..31: V -> Vall[cur+t]
// ---------------------------------------------------------------------------
__global__ __launch_bounds__(256) void norm_rope(unsigned short* __restrict__ Qh,
                                                 const unsigned short* __restrict__ Kh,
                                                 const unsigned short* __restrict__ Vh,
                                                 unsigned short* __restrict__ Kall,
                                                 unsigned short* __restrict__ Vall,
                                                 const float* __restrict__ qw,
                                                 const float* __restrict__ kw,
                                                 const int* __restrict__ seg,
                                                 const int* __restrict__ meta,
                                                 const int* __restrict__ cur_ptr)
{
    int rowid = blockIdx.x * 4 + (threadIdx.x >> 6);
    int lane = threadIdx.x & 63;
    int hh = rowid & 31;
    int bt = rowid >> 5;
    int t = bt & (Tc - 1);
    int b = bt >> 11;
    int cur = cur_ptr[0];

    if (hh >= 24) {   // V: plain cast-copy to merged buffer
        int kh = hh - 24;
        const unsigned short* in = Vh + ((size_t)bt * KHc + kh) * Hc;
        unsigned short* out = Vall + (((size_t)b * Sc + cur + t) * KHc + kh) * Hc;
        out[lane] = in[lane];
        out[lane + 64] = in[lane + 64];
        return;
    }

    const unsigned short* in;
    unsigned short* out;
    const float* wt;
    if (hh < 16) {
        unsigned short* p = Qh + ((size_t)bt * Nc + hh) * Hc;
        in = p; out = p; wt = qw;
    } else {
        int kh = hh - 16;
        in = Kh + ((size_t)bt * KHc + kh) * Hc;
        out = Kall + (((size_t)b * Sc + cur + t) * KHc + kh) * Hc;
        wt = kw;
    }
    float v1 = bf2f(in[lane]), v2 = bf2f(in[lane + 64]);
    float ssq = v1 * v1 + v2 * v2;
#pragma unroll
    for (int off = 1; off < 64; off <<= 1) ssq += __shfl_xor(ssq, off);
    float rinv = rsqrtf(ssq * (1.0f / Hc) + EPSc);

    int sg = seg[bt];
    long long pos = (sg != 0) ? (long long)(t - meta[b]) : (long long)(1 << 30);
    float posf = (float)(pos + (long long)cur);
    float inv_freq = exp2f(-(float)lane * (19.931568569324174f / 64.0f));
    float s, c;
    sincosf(posf * inv_freq, &s, &c);

    float n1 = wt[lane] * v1 * rinv;
    float n2 = wt[lane + 64] * v2 * rinv;
    out[lane]      = f2bf(n1 * c - n2 * s);
    out[lane + 64] = f2bf(n2 * c + n1 * s);
}

// ---------------------------------------------------------------------------
// MFMA flash attention. Block: 256 thr (4 waves), 128 q-rows, S-chunks of 64.
// Wave owns a 32-row strip (2 m-tiles). Q frags register-resident.
// ---------------------------------------------------------------------------
__global__ __launch_bounds__(256, 2) void flash_mfma(const unsigned short* __restrict__ Qb,
                                                     const unsigned short* __restrict__ Kall,
                                                     const unsigned short* __restrict__ Vall,
                                                     const int* __restrict__ seg,
                                                     const int* __restrict__ meta,
                                                     const int* __restrict__ cur_ptr,
                                                     unsigned short* __restrict__ Ob)
{
    __shared__ __align__(16) unsigned short Ks[64 * 152];    // [s][h], stride 152
    __shared__ __align__(16) unsigned short Vs[128 * 88];    // [h][s], stride 88
    __shared__ __align__(16) unsigned short Ps[128 * 88];    // [qrow][s], stride 88

    int tid = threadIdx.x;
    int lane = tid & 63, w = tid >> 6;
    int quad = lane >> 4, l15 = lane & 15;
    int bid = blockIdx.x;
    int qt = bid & 15;
    int n  = (bid >> 4) & 15;
    int b  = bid >> 8;
    int kh = n >> 1;
    int cur = cur_ptr[0];
    int startb = meta[Bc + b];
    int curT = cur + Tc;
    int t0 = qt * 128 + w * 32;

    // Q fragments: qf[mi][ks], A-layout (m=l15, k=quad*8+j within ks*32)
    short8 qf[2][4];
#pragma unroll
    for (int mi = 0; mi < 2; ++mi)
#pragma unroll
        for (int ks = 0; ks < 4; ++ks) {
            int row = t0 + mi * 16 + l15;
            U16x8 u;
            u.u = *(const uint4*)&Qb[((size_t)(b * Tc + row) * Nc + n) * Hc + ks * 32 + quad * 8];
            qf[mi][ks] = u.s8;
        }

    // per-row metadata: class code (2 bits x 8) and causal threshold
    int code = 0, ct[8];
#pragma unroll
    for (int mi = 0; mi < 2; ++mi)
#pragma unroll
        for (int reg = 0; reg < 4; ++reg) {
            int idx = mi * 4 + reg;
            int trow = t0 + mi * 16 + quad * 4 + reg;
            int sg = seg[b * Tc + trow];
            int cls = (sg == 0) ? 0 : ((sg == 1) ? 1 : 2);
            code |= cls << (2 * idx);
            ct[idx] = cur + trow;
        }

    float m_i[8], l_i[8];
#pragma unroll
    for (int i = 0; i < 8; ++i) { m_i[i] = -INFINITY; l_i[i] = 0.f; }
    float4v o[16];
#pragma unroll
    for (int i = 0; i < 16; ++i) o[i] = (float4v)0.f;

    for (int s0 = 0; s0 < Sc; s0 += 64) {
        __syncthreads();
        // stage K chunk: 64 x 128, padded rows
#pragma unroll
        for (int i = 0; i < 4; ++i) {
            int c = tid + 256 * i;
            int row = c >> 4, hp = c & 15;
            *(uint4*)&Ks[row * 152 + hp * 8] =
                *(const uint4*)&Kall[((size_t)(b * Sc + s0 + row) * KHc + kh) * Hc + hp * 8];
        }
        // stage V chunk transposed: Vs[h][s]
#pragma unroll
        for (int i = 0; i < 2; ++i) {
            int u = tid + 256 * i;
            int hg = u & 15, spair = u >> 4;
            size_t gbase = ((size_t)(b * Sc + s0 + spair * 2) * KHc + kh) * Hc + hg * 8;
            U16x8 a, bb;
            a.u  = *(const uint4*)&Vall[gbase];
            bb.u = *(const uint4*)&Vall[gbase + (size_t)KHc * Hc];
#pragma unroll
            for (int e = 0; e < 8; ++e) {
                unsigned val = (unsigned)a.us[e] | ((unsigned)bb.us[e] << 16);
                *(unsigned*)&Vs[(hg * 8 + e) * 88 + spair * 2] = val;
            }
        }
        __syncthreads();

        // QK^T: sacc[mi][j] = 16x16 tile (rows strip, cols s0+j*16..)
        float4v sacc[2][4];
#pragma unroll
        for (int mi = 0; mi < 2; ++mi)
#pragma unroll
            for (int j = 0; j < 4; ++j) sacc[mi][j] = (float4v)0.f;
#pragma unroll
        for (int j = 0; j < 4; ++j) {
#pragma unroll
            for (int ks = 0; ks < 4; ++ks) {
                short8 kf = *(const short8*)&Ks[(j * 16 + l15) * 152 + ks * 32 + quad * 8];
                sacc[0][j] = __builtin_amdgcn_mfma_f32_16x16x32_bf16(qf[0][ks], kf, sacc[0][j], 0, 0, 0);
                sacc[1][j] = __builtin_amdgcn_mfma_f32_16x16x32_bf16(qf[1][ks], kf, sacc[1][j], 0, 0, 0);
            }
        }

        // online softmax per row (row = quad*4+reg within mi-tile)
#pragma unroll
        for (int mi = 0; mi < 2; ++mi) {
#pragma unroll
            for (int reg = 0; reg < 4; ++reg) {
                int idx = mi * 4 + reg;
                int ctv = ct[idx];
                int clsv = (code >> (2 * idx)) & 3;
                float vals[4];
                float mloc = -INFINITY;
#pragma unroll
                for (int j = 0; j < 4; ++j) {
                    int s = s0 + j * 16 + l15;
                    int kvseg = (s >= startb && s < curT) ? 1 : 0;
                    bool ok = (s <= ctv) && (clsv == kvseg);
                    float v = ok ? sacc[mi][j][reg] * SCALEc : KMASKc;
                    vals[j] = v;
                    mloc = fmaxf(mloc, v);
                }
                mloc = fmaxf(mloc, __shfl_xor(mloc, 1));
                mloc = fmaxf(mloc, __shfl_xor(mloc, 2));
                mloc = fmaxf(mloc, __shfl_xor(mloc, 4));
                mloc = fmaxf(mloc, __shfl_xor(mloc, 8));
                float mnew = fmaxf(m_i[idx], mloc);
                float alpha = __expf(m_i[idx] - mnew);
                float ps = 0.f;
                int prow = w * 32 + mi * 16 + quad * 4 + reg;
#pragma unroll
                for (int j = 0; j < 4; ++j) {
                    float p = __expf(vals[j] - mnew);
                    ps += p;
                    Ps[prow * 88 + j * 16 + l15] = f2bf(p);
                }
                ps += __shfl_xor(ps, 1);
                ps += __shfl_xor(ps, 2);
                ps += __shfl_xor(ps, 4);
                ps += __shfl_xor(ps, 8);
                l_i[idx] = l_i[idx] * alpha + ps;
                m_i[idx] = mnew;
#pragma unroll
                for (int nt = 0; nt < 8; ++nt) o[mi * 8 + nt][reg] *= alpha;
            }
        }

        // PV: o[mi][nt] += P[strip, s-chunk] * V[s-chunk, h]
#pragma unroll
        for (int kk = 0; kk < 2; ++kk) {
            short8 pf0 = *(const short8*)&Ps[(w * 32 + l15) * 88 + kk * 32 + quad * 8];
            short8 pf1 = *(const short8*)&Ps[(w * 32 + 16 + l15) * 88 + kk * 32 + quad * 8];
#pragma unroll
            for (int nt = 0; nt < 8; ++nt) {
                short8 vf = *(const short8*)&Vs[(nt * 16 + l15) * 88 + kk * 32 + quad * 8];
                o[nt]     = __builtin_amdgcn_mfma_f32_16x16x32_bf16(pf0, vf, o[nt], 0, 0, 0);
                o[8 + nt] = __builtin_amdgcn_mfma_f32_16x16x32_bf16(pf1, vf, o[8 + nt], 0, 0, 0);
            }
        }
    }

    // epilogue: normalize and store bf16
#pragma unroll
    for (int mi = 0; mi < 2; ++mi)
#pragma unroll
        for (int reg = 0; reg < 4; ++reg) {
            float linv = 1.0f / l_i[mi * 4 + reg];
            int trow = t0 + mi * 16 + quad * 4 + reg;
            size_t base = ((size_t)(b * Tc + trow) * Nc + n) * Hc;
#pragma unroll
            for (int nt = 0; nt < 8; ++nt)
                Ob[base + nt * 16 + l15] = f2bf(o[mi * 8 + nt][reg] * linv);
        }
}

// ---------------------------------------------------------------------------
extern "C" void kernel_launch(void* const* d_in, const int* in_sizes, int n_in,
                              void* d_out, int out_size, void* d_ws, size_t ws_size,
                              hipStream_t stream)
{
    const float* x        = (const float*)d_in[0];
    const float* q_w      = (const float*)d_in[1];
    const float* k_w      = (const float*)d_in[2];
    const float* v_w      = (const float*)d_in[3];
    const float* o_w      = (const float*)d_in[4];
    const float* q_norm_w = (const float*)d_in[5];
    const float* k_norm_w = (const float*)d_in[6];
    const float* k_cache  = (const float*)d_in[7];
    const float* v_cache  = (const float*)d_in[8];
    const int*   seg      = (const int*)d_in[9];
    const int*   startind = (const int*)d_in[10];
    const int*   cur_ptr  = (const int*)d_in[11];
    (void)in_sizes; (void)n_in; (void)out_size; (void)ws_size;

    char* base = (char*)d_ws;
    int* meta = (int*)base;                                   //      1024 B
    unsigned short* Qh   = (unsigned short*)(base + 1024);            // 16.78 MB [4096][2048]
    unsigned short* Kh   = (unsigned short*)(base + 16778240);        //  8.39 MB [4096][1024]
    unsigned short* Vh   = (unsigned short*)(base + 25166848);        //  8.39 MB
    unsigned short* Kall = (unsigned short*)(base + 33555456);        //  8.39 MB [B][S][KH][H]
    unsigned short* Vall = (unsigned short*)(base + 41944064);        //  8.39 MB
    unsigned short* xb   = (unsigned short*)(base + 50332672);        // 16.78 MB [4096][2048]; reused as Ob
    unsigned short* qwT  = (unsigned short*)(base + 67109888);        //  8.39 MB [2048][2048]
    unsigned short* kwT  = (unsigned short*)(base + 75498496);        //  4.19 MB [1024][2048]
    unsigned short* vwT  = (unsigned short*)(base + 79692800);        //  4.19 MB
    unsigned short* owT  = (unsigned short*)(base + 83887104);        //  8.39 MB [2048][2048]
    unsigned short* Ob   = xb;

    meta_kernel<<<Bc, 256, 0, stream>>>(seg, startind, meta);

    cast_bf16<<<4096, 256, 0, stream>>>(x, xb);                       // 8.39M elems
    transpose_cast<<<dim3(64, 64), 256, 0, stream>>>(q_w, qwT, Dc, Nc * Hc);
    transpose_cast<<<dim3(32, 64), 256, 0, stream>>>(k_w, kwT, Dc, KHc * Hc);
    transpose_cast<<<dim3(32, 64), 256, 0, stream>>>(v_w, vwT, Dc, KHc * Hc);
    transpose_cast<<<dim3(64, 64), 256, 0, stream>>>(o_w, owT, Nc * Hc, Dc);

    gemm_mfma<<<dim3(16, 32), 256, 0, stream>>>(xb, qwT, Qh, Bc * Tc, Nc * Hc, Dc, 0);
    gemm_mfma<<<dim3(8, 32), 256, 0, stream>>>(xb, kwT, Kh, Bc * Tc, KHc * Hc, Dc, 0);
    gemm_mfma<<<dim3(8, 32), 256, 0, stream>>>(xb, vwT, Vh, Bc * Tc, KHc * Hc, Dc, 0);

    cache_cast<<<2048, 256, 0, stream>>>(k_cache, v_cache, Kall, Vall);

    norm_rope<<<Bc * Tc * 32 / 4, 256, 0, stream>>>(Qh, Kh, Vh, Kall, Vall,
                                                    q_norm_w, k_norm_w, seg, meta, cur_ptr);

    flash_mfma<<<Bc * Nc * (Tc / 128), 256, 0, stream>>>(Qh, Kall, Vall, seg, meta, cur_ptr, Ob);

    gemm_mfma<<<dim3(16, 32), 256, 0, stream>>>(Ob, owT, d_out, Bc * Tc, Dc, Nc * Hc, 1);
}

// Round 3
// 486.969 us; speedup vs baseline: 8.3725x; 1.2876x over previous
//
#include <hip/hip_runtime.h>
#include <climits>
#include <math.h>

#define Bc   2
#define Tc   2048
#define Dc   2048
#define Nc   16
#define KHc  8
#define Hc   128
#define Sc   2048

constexpr float EPSc   = 1e-6f;
constexpr float KMASKc = -0.7f * 3.4028234663852886e38f;
constexpr float SCALEc = 0.08838834764831843f;   // 1/sqrt(128)

typedef short short8 __attribute__((ext_vector_type(8)));
typedef float float4v __attribute__((ext_vector_type(4)));

union U16x8 { uint4 u; short8 s8; unsigned short us[8]; };

__device__ __forceinline__ unsigned short f2bf(float f) {
    union { float f; unsigned u; } v; v.f = f;
    unsigned r = v.u + 0x7FFFu + ((v.u >> 16) & 1u);
    return (unsigned short)(r >> 16);
}
__device__ __forceinline__ float bf2f(unsigned short u) {
    union { unsigned u; float f; } v; v.u = ((unsigned)u) << 16;
    return v.f;
}

// ---------------------------------------------------------------------------
// meta[b] = argmax(seg) first index; meta[Bc+b] = start
// ---------------------------------------------------------------------------
__global__ void meta_kernel(const int* __restrict__ seg,
                            const int* __restrict__ start_ind,
                            int* __restrict__ meta)
{
    int b = blockIdx.x;
    __shared__ int s_max, s_amax, s_nz;
    if (threadIdx.x == 0) { s_max = INT_MIN; s_amax = Tc; s_nz = Tc; }
    __syncthreads();
    int lmax = INT_MIN;
    for (int t = threadIdx.x; t < Tc; t += blockDim.x)
        lmax = max(lmax, seg[b * Tc + t]);
    atomicMax(&s_max, lmax);
    __syncthreads();
    int mv = s_max;
    int lamax = Tc, lnz = Tc;
    for (int t = threadIdx.x; t < Tc; t += blockDim.x) {
        int v = seg[b * Tc + t];
        if (v == mv) lamax = min(lamax, t);
        if (v != 0)  lnz   = min(lnz, t);
    }
    atomicMin(&s_amax, lamax);
    atomicMin(&s_nz, lnz);
    __syncthreads();
    if (threadIdx.x == 0) {
        meta[b] = s_amax;
        int st = start_ind[b];
        meta[Bc + b] = (st < 0) ? s_nz : st;
    }
}

// ---------------------------------------------------------------------------
// cast fp32 -> bf16, 8 elems/thread
// ---------------------------------------------------------------------------
__global__ void cast_bf16(const float* __restrict__ in, unsigned short* __restrict__ out)
{
    size_t base = ((size_t)blockIdx.x * 256 + threadIdx.x) * 8;
    float4 a = *(const float4*)&in[base];
    float4 b = *(const float4*)&in[base + 4];
    U16x8 o;
    o.us[0] = f2bf(a.x); o.us[1] = f2bf(a.y); o.us[2] = f2bf(a.z); o.us[3] = f2bf(a.w);
    o.us[4] = f2bf(b.x); o.us[5] = f2bf(b.y); o.us[6] = f2bf(b.z); o.us[7] = f2bf(b.w);
    *(uint4*)&out[base] = o.u;
}

// cache fill: Kall/Vall = bf16(cache), same flat layout
__global__ void cache_cast(const float* __restrict__ kc, const float* __restrict__ vc,
                           unsigned short* __restrict__ Kall, unsigned short* __restrict__ Vall)
{
    size_t base = ((size_t)blockIdx.x * 256 + threadIdx.x) * 8;
    {
        float4 a = *(const float4*)&kc[base];
        float4 b = *(const float4*)&kc[base + 4];
        U16x8 o;
        o.us[0] = f2bf(a.x); o.us[1] = f2bf(a.y); o.us[2] = f2bf(a.z); o.us[3] = f2bf(a.w);
        o.us[4] = f2bf(b.x); o.us[5] = f2bf(b.y); o.us[6] = f2bf(b.z); o.us[7] = f2bf(b.w);
        *(uint4*)&Kall[base] = o.u;
    }
    {
        float4 a = *(const float4*)&vc[base];
        float4 b = *(const float4*)&vc[base + 4];
        U16x8 o;
        o.us[0] = f2bf(a.x); o.us[1] = f2bf(a.y); o.us[2] = f2bf(a.z); o.us[3] = f2bf(a.w);
        o.us[4] = f2bf(b.x); o.us[5] = f2bf(b.y); o.us[6] = f2bf(b.z); o.us[7] = f2bf(b.w);
        *(uint4*)&Vall[base] = o.u;
    }
}

// ---------------------------------------------------------------------------
// transpose + cast: in fp32 [R][C] -> out bf16 [C][R]
// ---------------------------------------------------------------------------
__global__ __launch_bounds__(256) void transpose_cast(const float* __restrict__ in,
                                                      unsigned short* __restrict__ out,
                                                      int R, int C)
{
    __shared__ float tile[32][33];
    int tid = threadIdx.x;
    int c0 = blockIdx.x * 32, r0 = blockIdx.y * 32;
#pragma unroll
    for (int i = 0; i < 4; ++i) {
        int row = (tid >> 5) + i * 8, col = tid & 31;
        tile[row][col] = in[(size_t)(r0 + row) * C + c0 + col];
    }
    __syncthreads();
#pragma unroll
    for (int i = 0; i < 4; ++i) {
        int rowo = (tid >> 5) + i * 8, colo = tid & 31;
        out[(size_t)(c0 + rowo) * R + r0 + colo] = f2bf(tile[colo][rowo]);
    }
}

// ---------------------------------------------------------------------------
// V transpose: Vall [b][s][kh][h] -> Vt [b][kh][h][s]  (bf16)
// lanes walk h fastest -> coalesced reads; strided uint4 writes absorbed by L2
// ---------------------------------------------------------------------------
__global__ void vtrans(const unsigned short* __restrict__ Vall, unsigned short* __restrict__ Vt)
{
    int gid = blockIdx.x * 256 + threadIdx.x;        // 524288 total
    int h  = gid & 127;
    int s8 = ((gid >> 7) & 255) * 8;
    int kh = (gid >> 15) & 7;
    int b  = gid >> 18;
    unsigned short tmp[8];
#pragma unroll
    for (int e = 0; e < 8; ++e)
        tmp[e] = Vall[((size_t)(b * Sc + s8 + e) * KHc + kh) * Hc + h];
    *(uint4*)&Vt[(((size_t)b * KHc + kh) * Hc + h) * Sc + s8] = *(uint4*)tmp;
}

// ---------------------------------------------------------------------------
// bf16 MFMA GEMM (m97 structure): C[M,N] = A[M,K] * BT[N,K]^T.
// 128x128 tile, BK=32, 256 threads (4 waves 2x2), global_load_lds width 16,
// XOR k-part swizzle keeps frag ds_read_b128 conflict-free on unpadded LDS.
// ---------------------------------------------------------------------------
__global__ __launch_bounds__(256, 2) void gemm_mfma(const unsigned short* __restrict__ A,
                                                    const unsigned short* __restrict__ BT,
                                                    void* __restrict__ Cout,
                                                    int M, int N, int K, int out_fp32)
{
    __shared__ __align__(16) unsigned short As[128 * 32];
    __shared__ __align__(16) unsigned short Bs[128 * 32];
    int tid = threadIdx.x;
    int lane = tid & 63, w = tid >> 6;
    int quad = lane >> 4, l15 = lane & 15;
    int bm = blockIdx.y * 128, bn = blockIdx.x * 128;
    int wm = (w >> 1) * 64, wn = (w & 1) * 64;

    int srow = lane >> 2;          // 0..15 within a 1KB chunk
    int pl   = lane & 3;           // LDS k-part slot
    int sw   = (quad ^ ((l15 >> 1) & 3)) * 8;   // swizzled frag read offset

    float4v acc[16];
#pragma unroll
    for (int i = 0; i < 16; ++i) acc[i] = (float4v)0.f;

    for (int k0 = 0; k0 < K; k0 += 32) {
        __syncthreads();
#pragma unroll
        for (int c = 0; c < 2; ++c) {
            int j = w * 2 + c;                 // chunk 0..7
            int row = j * 16 + srow;
            int pg = pl ^ ((row >> 1) & 3);    // global k-part for this LDS slot
            __builtin_amdgcn_global_load_lds(
                (__attribute__((address_space(1))) void*)(A + (size_t)(bm + row) * K + k0 + pg * 8),
                (__attribute__((address_space(3))) void*)(As + j * 512), 16, 0, 0);
            __builtin_amdgcn_global_load_lds(
                (__attribute__((address_space(1))) void*)(BT + (size_t)(bn + row) * K + k0 + pg * 8),
                (__attribute__((address_space(3))) void*)(Bs + j * 512), 16, 0, 0);
        }
        __syncthreads();
        short8 af[4];
#pragma unroll
        for (int mi = 0; mi < 4; ++mi)
            af[mi] = *(const short8*)&As[(wm + mi * 16 + l15) * 32 + sw];
#pragma unroll
        for (int ni = 0; ni < 4; ++ni) {
            short8 bf = *(const short8*)&Bs[(wn + ni * 16 + l15) * 32 + sw];
#pragma unroll
            for (int mi = 0; mi < 4; ++mi)
                acc[mi * 4 + ni] = __builtin_amdgcn_mfma_f32_16x16x32_bf16(af[mi], bf, acc[mi * 4 + ni], 0, 0, 0);
        }
    }

#pragma unroll
    for (int mi = 0; mi < 4; ++mi)
#pragma unroll
        for (int ni = 0; ni < 4; ++ni)
#pragma unroll
            for (int reg = 0; reg < 4; ++reg) {
                int row = bm + wm + mi * 16 + quad * 4 + reg;
                int col = bn + wn + ni * 16 + l15;
                float v = acc[mi * 4 + ni][reg];
                if (out_fp32) ((float*)Cout)[(size_t)row * N + col] = v;
                else ((unsigned short*)Cout)[(size_t)row * N + col] = f2bf(v);
            }
}

// ---------------------------------------------------------------------------
// RMSNorm + RoPE on the fused QKV buffer (ld = 4096).
// slot 0..15: Q in-place; 16..23: K -> Kall[cur+t]; 24..31: V -> Vall[cur+t]
// ---------------------------------------------------------------------------
__global__ __launch_bounds__(256) void norm_rope(unsigned short* __restrict__ QKVh,
                                                 unsigned short* __restrict__ Kall,
                                                 unsigned short* __restrict__ Vall,
                                                 const float* __restrict__ qw,
                                                 const float* __restrict__ kw,
                                                 const int* __restrict__ seg,
                                                 const int* __restrict__ meta,
                                                 const int* __restrict__ cur_ptr)
{
    int rowid = blockIdx.x * 4 + (threadIdx.x >> 6);
    int lane = threadIdx.x & 63;
    int hh = rowid & 31;
    int bt = rowid >> 5;
    int t = bt & (Tc - 1);
    int b = bt >> 11;
    int cur = cur_ptr[0];

    if (hh >= 24) {   // V: copy to merged cache buffer
        int kh = hh - 24;
        const unsigned short* in = QKVh + (size_t)bt * 4096 + 3072 + kh * Hc;
        unsigned short* out = Vall + (((size_t)b * Sc + cur + t) * KHc + kh) * Hc;
        out[lane] = in[lane];
        out[lane + 64] = in[lane + 64];
        return;
    }

    const unsigned short* in;
    unsigned short* out;
    const float* wt;
    if (hh < 16) {
        unsigned short* p = QKVh + (size_t)bt * 4096 + hh * Hc;
        in = p; out = p; wt = qw;
    } else {
        int kh = hh - 16;
        in = QKVh + (size_t)bt * 4096 + 2048 + kh * Hc;
        out = Kall + (((size_t)b * Sc + cur + t) * KHc + kh) * Hc;
        wt = kw;
    }
    float v1 = bf2f(in[lane]), v2 = bf2f(in[lane + 64]);
    float ssq = v1 * v1 + v2 * v2;
#pragma unroll
    for (int off = 1; off < 64; off <<= 1) ssq += __shfl_xor(ssq, off);
    float rinv = rsqrtf(ssq * (1.0f / Hc) + EPSc);

    int sg = seg[bt];
    long long pos = (sg != 0) ? (long long)(t - meta[b]) : (long long)(1 << 30);
    float posf = (float)(pos + (long long)cur);
    float inv_freq = exp2f(-(float)lane * (19.931568569324174f / 64.0f));
    float s, c;
    sincosf(posf * inv_freq, &s, &c);

    float n1 = wt[lane] * v1 * rinv;
    float n2 = wt[lane + 64] * v2 * rinv;
    out[lane]      = f2bf(n1 * c - n2 * s);
    out[lane + 64] = f2bf(n2 * c + n1 * s);
}

// ---------------------------------------------------------------------------
// MFMA flash attention with causal chunk-skip. 256 thr / 128 q-rows / S-chunk 64.
// qt remapped so paired blocks (bid, bid+256) have complementary work.
// V staged from pre-transposed Vt (conflict-free). Q read from fused QKVh.
// ---------------------------------------------------------------------------
__global__ __launch_bounds__(256, 2) void flash_mfma(const unsigned short* __restrict__ Qb,
                                                     const unsigned short* __restrict__ Kall,
                                                     const unsigned short* __restrict__ Vt,
                                                     const int* __restrict__ seg,
                                                     const int* __restrict__ meta,
                                                     const int* __restrict__ cur_ptr,
                                                     unsigned short* __restrict__ Ob)
{
    __shared__ __align__(16) unsigned short Ks[64 * 152];    // [s][h], stride 152
    __shared__ __align__(16) unsigned short Vs[128 * 88];    // [h][s], stride 88
    __shared__ __align__(16) unsigned short Ps[128 * 88];    // [qrow][s], stride 88

    int tid = threadIdx.x;
    int lane = tid & 63, w = tid >> 6;
    int quad = lane >> 4, l15 = lane & 15;
    int bid = blockIdx.x;
    int raw = bid & 15;
    int n  = (bid >> 4) & 15;
    int b  = bid >> 8;
    int qt = (b == 0) ? raw : (15 - raw);    // pair bid & bid+256 -> balanced work
    int kh = n >> 1;
    int cur = cur_ptr[0];
    int startb = meta[Bc + b];
    int curT = cur + Tc;
    int t0 = qt * 128 + w * 32;

    // Q fragments (A-layout), ld 4096
    short8 qf[2][4];
#pragma unroll
    for (int mi = 0; mi < 2; ++mi)
#pragma unroll
        for (int ks = 0; ks < 4; ++ks) {
            int row = t0 + mi * 16 + l15;
            U16x8 u;
            u.u = *(const uint4*)&Qb[(size_t)(b * Tc + row) * 4096 + n * Hc + ks * 32 + quad * 8];
            qf[mi][ks] = u.s8;
        }

    int code = 0, ct[8];
#pragma unroll
    for (int mi = 0; mi < 2; ++mi)
#pragma unroll
        for (int reg = 0; reg < 4; ++reg) {
            int idx = mi * 4 + reg;
            int trow = t0 + mi * 16 + quad * 4 + reg;
            int sg = seg[b * Tc + trow];
            int cls = (sg == 0) ? 0 : ((sg == 1) ? 1 : 2);
            code |= cls << (2 * idx);
            ct[idx] = cur + trow;
        }
    bool allseg1 = (code == 0x5555);

    float m_i[8], l_i[8];
#pragma unroll
    for (int i = 0; i < 8; ++i) { m_i[i] = -INFINITY; l_i[i] = 0.f; }
    float4v o[16];
#pragma unroll
    for (int i = 0; i < 16; ++i) o[i] = (float4v)0.f;

    // chunks beyond the causal frontier contribute exactly 0 -> skip
    int s_end = min(Sc, cur + qt * 128 + 128);

    for (int s0 = 0; s0 < s_end; s0 += 64) {
        __syncthreads();
        // stage K chunk: 64 x 128 (row-major, padded 152)
#pragma unroll
        for (int i = 0; i < 4; ++i) {
            int c = tid + 256 * i;
            int row = c >> 4, hp = c & 15;
            *(uint4*)&Ks[row * 152 + hp * 8] =
                *(const uint4*)&Kall[((size_t)(b * Sc + s0 + row) * KHc + kh) * Hc + hp * 8];
        }
        // stage V chunk from pre-transposed Vt: Vs[h][s]
#pragma unroll
        for (int i = 0; i < 4; ++i) {
            int u = tid + 256 * i;
            int h = u >> 3, hp = u & 7;
            *(uint4*)&Vs[h * 88 + hp * 8] =
                *(const uint4*)&Vt[((size_t)(b * KHc + kh) * Hc + h) * Sc + s0 + hp * 8];
        }
        __syncthreads();

        // QK^T
        float4v sacc[2][4];
#pragma unroll
        for (int mi = 0; mi < 2; ++mi)
#pragma unroll
            for (int j = 0; j < 4; ++j) sacc[mi][j] = (float4v)0.f;
#pragma unroll
        for (int j = 0; j < 4; ++j) {
#pragma unroll
            for (int ks = 0; ks < 4; ++ks) {
                short8 kf = *(const short8*)&Ks[(j * 16 + l15) * 152 + ks * 32 + quad * 8];
                sacc[0][j] = __builtin_amdgcn_mfma_f32_16x16x32_bf16(qf[0][ks], kf, sacc[0][j], 0, 0, 0);
                sacc[1][j] = __builtin_amdgcn_mfma_f32_16x16x32_bf16(qf[1][ks], kf, sacc[1][j], 0, 0, 0);
            }
        }

        bool fullok = allseg1 && (s0 >= startb) && (s0 + 63 <= cur + t0) && (s0 + 63 < curT);

        // online softmax per row
#pragma unroll
        for (int mi = 0; mi < 2; ++mi) {
#pragma unroll
            for (int reg = 0; reg < 4; ++reg) {
                int idx = mi * 4 + reg;
                float vals[4];
                float mloc = -INFINITY;
                if (fullok) {
#pragma unroll
                    for (int j = 0; j < 4; ++j) {
                        vals[j] = sacc[mi][j][reg] * SCALEc;
                        mloc = fmaxf(mloc, vals[j]);
                    }
                } else {
                    int ctv = ct[idx];
                    int clsv = (code >> (2 * idx)) & 3;
#pragma unroll
                    for (int j = 0; j < 4; ++j) {
                        int s = s0 + j * 16 + l15;
                        int kvseg = (s >= startb && s < curT) ? 1 : 0;
                        bool ok = (s <= ctv) && (clsv == kvseg);
                        float v = ok ? sacc[mi][j][reg] * SCALEc : KMASKc;
                        vals[j] = v;
                        mloc = fmaxf(mloc, v);
                    }
                }
                mloc = fmaxf(mloc, __shfl_xor(mloc, 1));
                mloc = fmaxf(mloc, __shfl_xor(mloc, 2));
                mloc = fmaxf(mloc, __shfl_xor(mloc, 4));
                mloc = fmaxf(mloc, __shfl_xor(mloc, 8));
                float mnew = fmaxf(m_i[idx], mloc);
                float alpha = __expf(m_i[idx] - mnew);
                float ps = 0.f;
                int prow = w * 32 + mi * 16 + quad * 4 + reg;
#pragma unroll
                for (int j = 0; j < 4; ++j) {
                    float p = __expf(vals[j] - mnew);
                    ps += p;
                    Ps[prow * 88 + j * 16 + l15] = f2bf(p);
                }
                ps += __shfl_xor(ps, 1);
                ps += __shfl_xor(ps, 2);
                ps += __shfl_xor(ps, 4);
                ps += __shfl_xor(ps, 8);
                l_i[idx] = l_i[idx] * alpha + ps;
                m_i[idx] = mnew;
#pragma unroll
                for (int nt = 0; nt < 8; ++nt) o[mi * 8 + nt][reg] *= alpha;
            }
        }

        // PV
#pragma unroll
        for (int kk = 0; kk < 2; ++kk) {
            short8 pf0 = *(const short8*)&Ps[(w * 32 + l15) * 88 + kk * 32 + quad * 8];
            short8 pf1 = *(const short8*)&Ps[(w * 32 + 16 + l15) * 88 + kk * 32 + quad * 8];
#pragma unroll
            for (int nt = 0; nt < 8; ++nt) {
                short8 vf = *(const short8*)&Vs[(nt * 16 + l15) * 88 + kk * 32 + quad * 8];
                o[nt]     = __builtin_amdgcn_mfma_f32_16x16x32_bf16(pf0, vf, o[nt], 0, 0, 0);
                o[8 + nt] = __builtin_amdgcn_mfma_f32_16x16x32_bf16(pf1, vf, o[8 + nt], 0, 0, 0);
            }
        }
    }

#pragma unroll
    for (int mi = 0; mi < 2; ++mi)
#pragma unroll
        for (int reg = 0; reg < 4; ++reg) {
            float linv = 1.0f / l_i[mi * 4 + reg];
            int trow = t0 + mi * 16 + quad * 4 + reg;
            size_t base = ((size_t)(b * Tc + trow) * Nc + n) * Hc;
#pragma unroll
            for (int nt = 0; nt < 8; ++nt)
                Ob[base + nt * 16 + l15] = f2bf(o[mi * 8 + nt][reg] * linv);
        }
}

// ---------------------------------------------------------------------------
extern "C" void kernel_launch(void* const* d_in, const int* in_sizes, int n_in,
                              void* d_out, int out_size, void* d_ws, size_t ws_size,
                              hipStream_t stream)
{
    const float* x        = (const float*)d_in[0];
    const float* q_w      = (const float*)d_in[1];
    const float* k_w      = (const float*)d_in[2];
    const float* v_w      = (const float*)d_in[3];
    const float* o_w      = (const float*)d_in[4];
    const float* q_norm_w = (const float*)d_in[5];
    const float* k_norm_w = (const float*)d_in[6];
    const float* k_cache  = (const float*)d_in[7];
    const float* v_cache  = (const float*)d_in[8];
    const int*   seg      = (const int*)d_in[9];
    const int*   startind = (const int*)d_in[10];
    const int*   cur_ptr  = (const int*)d_in[11];
    (void)in_sizes; (void)n_in; (void)out_size; (void)ws_size;

    char* base = (char*)d_ws;
    int* meta = (int*)base;                                          //      1024 B
    unsigned short* QKVh = (unsigned short*)(base + 1024);           // 33.55 MB [4096][4096]
    unsigned short* Kall = (unsigned short*)(base + 33555456);       //  8.39 MB [B][S][KH][H]
    unsigned short* Vall = (unsigned short*)(base + 41944064);       //  8.39 MB
    unsigned short* Vt   = (unsigned short*)(base + 50332672);       //  8.39 MB [B][KH][H][S]
    unsigned short* xb   = (unsigned short*)(base + 58721280);       // 16.78 MB [4096][2048]; reused as Ob
    unsigned short* qkvwT= (unsigned short*)(base + 75498496);       // 16.78 MB [4096][2048] (Q|K|V rows)
    unsigned short* owT  = (unsigned short*)(base + 92275712);       //  8.39 MB [2048][2048]
    unsigned short* Ob   = xb;

    meta_kernel<<<Bc, 256, 0, stream>>>(seg, startind, meta);

    cast_bf16<<<4096, 256, 0, stream>>>(x, xb);
    transpose_cast<<<dim3(64, 64), 256, 0, stream>>>(q_w, qkvwT, Dc, Nc * Hc);
    transpose_cast<<<dim3(32, 64), 256, 0, stream>>>(k_w, qkvwT + (size_t)2048 * 2048, Dc, KHc * Hc);
    transpose_cast<<<dim3(32, 64), 256, 0, stream>>>(v_w, qkvwT + (size_t)3072 * 2048, Dc, KHc * Hc);
    transpose_cast<<<dim3(64, 64), 256, 0, stream>>>(o_w, owT, Nc * Hc, Dc);

    // fused QKV projection: [4096 x 2048] @ [2048 x 4096]
    gemm_mfma<<<dim3(32, 32), 256, 0, stream>>>(xb, qkvwT, QKVh, Bc * Tc, 4096, Dc, 0);

    cache_cast<<<2048, 256, 0, stream>>>(k_cache, v_cache, Kall, Vall);

    norm_rope<<<Bc * Tc * 32 / 4, 256, 0, stream>>>(QKVh, Kall, Vall,
                                                    q_norm_w, k_norm_w, seg, meta, cur_ptr);

    vtrans<<<2048, 256, 0, stream>>>(Vall, Vt);

    flash_mfma<<<Bc * Nc * (Tc / 128), 256, 0, stream>>>(QKVh, Kall, Vt, seg, meta, cur_ptr, Ob);

    gemm_mfma<<<dim3(16, 32), 256, 0, stream>>>(Ob, owT, d_out, Bc * Tc, Dc, Nc * Hc, 1);
}